// Round 1
// baseline (353.293 us; speedup 1.0000x reference)
//
#include <hip/hip_runtime.h>
#include <hip/hip_bf16.h>

// Problem constants: mp [1, 21, 16, 256, 256] fp32
#define CC   21
#define DDp  16
#define HH   256
#define WW   256
#define HWp  (HH * WW)
#define DHW  (DDp * HWp)

// Tile: full D per workgroup; 8 (H) x 32 (W) spatial tile, halo 2 per side.
#define TW 32
#define TH 8
#define DP 20           // 16 + 4
#define HP 12           // 8 + 4
#define WP 36           // 32 + 4

// Separable 5x5x5 box blur with replicate padding, per channel.
// Writes blurred * (1/125) into out (laid out same as input).
__global__ __launch_bounds__(256) void blur_kernel(const float* __restrict__ mp,
                                                   float* __restrict__ out) {
    __shared__ float A[DP * HP * WP];   // raw padded tile (8640 floats), reused for stage-2 result
    __shared__ float B[DP * HP * TW];   // W-blurred (7680 floats)

    const int wt = blockIdx.x;          // 0..7
    const int ht = blockIdx.y;          // 0..31
    const int c  = blockIdx.z;          // 0..20
    const int w0 = wt * TW;
    const int h0 = ht * TH;
    const int tid = threadIdx.x;
    const float* __restrict__ src = mp + (size_t)c * DHW;

    // Stage 0: load padded raw tile with replicate clamp
    for (int i = tid; i < DP * HP * WP; i += 256) {
        int px = i % WP;
        int t  = i / WP;
        int py = t % HP;
        int dz = t / HP;
        int d = dz - 2;       d = max(0, min(DDp - 1, d));
        int h = h0 + py - 2;  h = max(0, min(HH  - 1, h));
        int w = w0 + px - 2;  w = max(0, min(WW  - 1, w));
        A[i] = src[d * HWp + h * WW + w];
    }
    __syncthreads();

    // Stage 1: blur along W: B[dz][py][x] = sum_{j=0..4} A[dz][py][x+j]
    for (int i = tid; i < DP * HP * TW; i += 256) {
        int x  = i & (TW - 1);
        int t  = i / TW;
        int py = t % HP;
        int dz = t / HP;
        const float* a = &A[(dz * HP + py) * WP + x];
        B[i] = a[0] + a[1] + a[2] + a[3] + a[4];
    }
    __syncthreads();

    // Stage 2: blur along H: A2[dz][y][x] = sum_{j=0..4} B[dz][y+j][x]
    // (A2 overlays A's storage; stage 2 reads only B — no hazard)
    for (int i = tid; i < DP * TH * TW; i += 256) {
        int x  = i & (TW - 1);
        int t  = i / TW;
        int y  = t % TH;
        int dz = t / TH;
        const float* b = &B[(dz * HP + y) * TW + x];
        A[i] = b[0] + b[TW] + b[2 * TW] + b[3 * TW] + b[4 * TW];
    }
    __syncthreads();

    // Stage 3: blur along D, scale by 1/125, write out
    for (int i = tid; i < DDp * TH * TW; i += 256) {
        int x = i & (TW - 1);
        int t = i / TW;
        int y = t % TH;
        int d = t / TH;
        const float* a = &A[(d * TH + y) * TW + x];
        float v = (a[0] + a[TH * TW] + a[2 * TH * TW] + a[3 * TH * TW] + a[4 * TH * TW])
                  * (1.0f / 125.0f);
        out[(size_t)c * DHW + d * HWp + (h0 + y) * WW + (w0 + x)] = v;
    }
}

// Per-pixel channel normalize + weighted-median selection, in place on `y`.
// Each thread owns one (d,h,w) pixel: reads its 21 channel values, then writes
// its 21 outputs — disjoint address sets per thread, reads precede writes.
__global__ __launch_bounds__(256) void median_kernel(float* __restrict__ y) {
    const int pix = blockIdx.x * 256 + threadIdx.x;   // 0 .. DHW-1

    float v[CC];
    float total = 0.f;
#pragma unroll
    for (int c = 0; c < CC; c++) {
        v[c] = y[(size_t)c * DHW + pix];
        total += v[c];
    }
    const float inv = 1.0f / total;

    float s = 0.f;
    int med0 = 0;   // last c with yn>0 && s<0.5, default 0
    int med1 = 0;   // first c>0 with s>0.5, default 0
#pragma unroll
    for (int c = 0; c < CC; c++) {
        float yn = v[c] * inv;
        s += yn;
        if (yn > 0.f && s < 0.5f) med0 = c;
        if (med1 == 0 && c > 0 && s > 0.5f) med1 = c;
    }

#pragma unroll
    for (int c = 0; c < CC; c++) {
        float yn = v[c] * inv;
        y[(size_t)c * DHW + pix] = (c == med0 || c == med1) ? yn : 0.f;
    }
}

extern "C" void kernel_launch(void* const* d_in, const int* in_sizes, int n_in,
                              void* d_out, int out_size, void* d_ws, size_t ws_size,
                              hipStream_t stream) {
    const float* mp = (const float*)d_in[0];
    float* out = (float*)d_out;

    dim3 bgrid(WW / TW, HH / TH, CC);   // 8 x 32 x 21
    blur_kernel<<<bgrid, 256, 0, stream>>>(mp, out);

    median_kernel<<<DHW / 256, 256, 0, stream>>>(out);
}